// Round 3
// baseline (425.690 us; speedup 1.0000x reference)
//
#include <hip/hip_runtime.h>

// GPConv1d: out[b,o,kb,w] = sum_{i,j,c,v} G[i,j,kb] W[v,c,o,i] xpad[b,c,j,w+v] + bias[o,kb]
// GEMM view: out[ok][b,w] = sum_kd kern[ok][kd] X[kd][b,w], M=512, N=32768, K=2560
// R3: (a) Bs XOR-swizzle (T2): ASTR 72->64, 16B colslot ^= (row&7) both sides ->
//     kills the 8-way conflict on B-frag reads (5.27M cyc measured, exact-match model).
//     (b) Occupancy 2->3 waves/SIMD: x-window staging split into two half-windows
//     with disjoint register live ranges (16+24 peak vs 40), Bs double-buffered so
//     the window store happens inside v=3/v=4 phases (1 barrier per cjb, 8 total).
//     __launch_bounds__(256,3).
//   - A (kern, 2.6 MB, L2-resident) in register double-buffer, frag-coalesced
//     tiles from build_kern, prefetch distance 1 phase, compiler-managed vmcnt.
//   - T5 setprio around MFMA clusters.

#define C_    64
#define L_    4096
#define PAD_  2
#define OKch  512
#define KD_   2560

#define BM    128
#define BN    128
#define BKCJ  64
#define NCJB  8
#define NV    5
#define TILE  8192      // kern tile: 128 rows x 64 cols (16 KB), frag-coalesced
#define WIN   132       // Bs rows: w0-2 .. w0+129
#define BSZ   (WIN * 64)  // one Bs buffer: 8448 elems = 16896 B

typedef __bf16 bf16x8 __attribute__((ext_vector_type(8)));
typedef float floatx4 __attribute__((ext_vector_type(4)));

__device__ __forceinline__ unsigned short f2bf(float f) {
    unsigned int u = __float_as_uint(f);
    u += 0x7FFFu + ((u >> 16) & 1u);
    return (unsigned short)(u >> 16);
}

#define WAIT_LGKM_0() asm volatile("s_waitcnt lgkmcnt(0)" ::: "memory")

__device__ __forceinline__ void barrier_raw() {
    asm volatile("" ::: "memory");
    __builtin_amdgcn_sched_barrier(0);
    __builtin_amdgcn_s_barrier();
    __builtin_amdgcn_sched_barrier(0);
    asm volatile("" ::: "memory");
}

// ---- kernel 1: build kern in fragment-coalesced tile layout, 8 outputs/thread.
__global__ __launch_bounds__(256) void build_kern(
    const float* __restrict__ W, const float* __restrict__ G,
    unsigned short* __restrict__ kernT)
{
    const int idx  = blockIdx.x * 256 + threadIdx.x;  // 0..163839
    const int lrow = idx & 15;
    const int quad = (idx >> 4) & 3;
    const int f    = (idx >> 6) & 15;
    const int mq   = f >> 1;
    const int kk2  = f & 1;
    const int t    = idx >> 10;          // (y*8+cjb)*5+v, 0..159
    const int v    = t % 5;
    const int tc   = t / 5;
    const int cjb  = tc & 7;
    const int y    = tc >> 3;
    const int m    = (mq << 4) | lrow;
    const int ok   = (y << 7) | m;
    const int o    = ok >> 3;
    const int kb   = ok & 7;
    const int c    = (cjb << 3) | (kk2 << 2) | quad;

    const float* Wp = W + (((v * C_ + c) * 64 + o) << 3);  // 8 i-contiguous
    const float4 w0 = *(const float4*)Wp;
    const float4 w1 = *(const float4*)(Wp + 4);
    const float w[8] = {w0.x, w0.y, w0.z, w0.w, w1.x, w1.y, w1.z, w1.w};

    unsigned int pk[4];
    #pragma unroll
    for (int j = 0; j < 8; j++) {
        float s = 0.f;
        #pragma unroll
        for (int i = 0; i < 8; i++)
            s += G[i * 64 + j * 8 + kb] * w[i];
        const unsigned short h = f2bf(s);
        if (j & 1) pk[j >> 1] |= (unsigned int)h << 16;
        else       pk[j >> 1]  = h;
    }
    uint4 uu; uu.x = pk[0]; uu.y = pk[1]; uu.z = pk[2]; uu.w = pk[3];
    *reinterpret_cast<uint4*>(
        &kernT[((size_t)t << 13) + (f << 9) + (quad << 7) + (lrow << 3)]) = uu;
}

// ---- x-window staging, split halves. Items: (kgrp=idx/132, nn=idx%132),
// halfA = idx 0..511, halfB = idx 512..1023, tail = idx 1024..1055.
__device__ __forceinline__ void bi_half(const float* xb, int cj0, int w0,
                                        int base, float br[2][8]) {
    const int tid = threadIdx.x;
    #pragma unroll
    for (int u = 0; u < 2; u++) {
        const int idx  = base + u * 256 + tid;
        const int kgrp = idx / WIN;
        const int nn   = idx - kgrp * WIN;
        int ws = w0 - PAD_ + nn;
        ws = ws < 0 ? 0 : (ws > (L_ - 1) ? (L_ - 1) : ws);
        const float* xp = xb + ((size_t)(cj0 + (kgrp << 3)) << 12) + (size_t)ws;
        #pragma unroll
        for (int r = 0; r < 8; r++)
            br[u][r] = xp[(size_t)r << 12];
    }
}

__device__ __forceinline__ void bi_tail(const float* xb, int cj0, int w0,
                                        float brT[8]) {
    const int tid = threadIdx.x;
    if ((tid & 7) == 0) {
        const int idx  = 1024 + ((tid >> 6) << 3) + ((tid >> 3) & 7);
        const int kgrp = idx / WIN;
        const int nn   = idx - kgrp * WIN;
        int ws = w0 - PAD_ + nn;
        ws = ws < 0 ? 0 : (ws > (L_ - 1) ? (L_ - 1) : ws);
        const float* xp = xb + ((size_t)(cj0 + (kgrp << 3)) << 12) + (size_t)ws;
        #pragma unroll
        for (int r = 0; r < 8; r++)
            brT[r] = xp[(size_t)r << 12];
    }
}

// store one item: row nn, 16B colslot kgrp XOR-swizzled by (nn&7)
__device__ __forceinline__ void st_item(unsigned short* Bw, int kgrp, int nn,
                                        int w0, const float br[8]) {
    const bool inb = (unsigned)(w0 - PAD_ + nn) < (unsigned)L_;
    unsigned int pk[4];
    #pragma unroll
    for (int r = 0; r < 8; r++) {
        const unsigned short h = f2bf(inb ? br[r] : 0.0f);
        if (r & 1) pk[r >> 1] |= (unsigned int)h << 16;
        else       pk[r >> 1]  = h;
    }
    uint4 uu; uu.x = pk[0]; uu.y = pk[1]; uu.z = pk[2]; uu.w = pk[3];
    *reinterpret_cast<uint4*>(&Bw[(nn << 6) + ((kgrp ^ (nn & 7)) << 3)]) = uu;
}

__device__ __forceinline__ void st_half(unsigned short* Bw, int base,
                                        const float br[2][8], int w0) {
    const int tid = threadIdx.x;
    #pragma unroll
    for (int u = 0; u < 2; u++) {
        const int idx  = base + u * 256 + tid;
        const int kgrp = idx / WIN;
        const int nn   = idx - kgrp * WIN;
        st_item(Bw, kgrp, nn, w0, br[u]);
    }
}

__device__ __forceinline__ void st_tail(unsigned short* Bw, const float brT[8],
                                        int w0) {
    const int tid = threadIdx.x;
    if ((tid & 7) == 0) {
        const int idx  = 1024 + ((tid >> 6) << 3) + ((tid >> 3) & 7);
        const int kgrp = idx / WIN;
        const int nn   = idx - kgrp * WIN;
        st_item(Bw, kgrp, nn, w0, brT);
    }
}

// ---- A-frag load: 8 contiguous-coalesced 16B loads into regs.
__device__ __forceinline__ void a_load(const unsigned short* t, int wb,
                                       bf16x8 r[8]) {
    #pragma unroll
    for (int f = 0; f < 8; f++)
        r[f] = *reinterpret_cast<const bf16x8*>(t + (f << 9) + wb);
}

__device__ __forceinline__ void compute_phase(
    const bf16x8 a[8], const unsigned short* BsR,
    int wn, int lrow, int quad, int v, floatx4 acc[4][4])
{
    const int s7  = (lrow + v) & 7;          // (row&7): wn, nt*16 are 0 mod 8
    const int rb0 = (wn + lrow + v) << 6;
    #pragma unroll
    for (int kk2 = 0; kk2 < 2; kk2++) {
        const int col = (((kk2 << 2) | quad) ^ s7) << 3;
        bf16x8 bfr[4];
        #pragma unroll
        for (int nt = 0; nt < 4; nt++)
            bfr[nt] = *reinterpret_cast<const bf16x8*>(
                &BsR[rb0 + (nt << 10) + col]);
        __builtin_amdgcn_s_setprio(1);
        #pragma unroll
        for (int mt = 0; mt < 4; mt++)
            #pragma unroll
            for (int nt = 0; nt < 4; nt++)
                acc[mt][nt] = __builtin_amdgcn_mfma_f32_16x16x32_bf16(
                    a[mt * 2 + kk2], bfr[nt], acc[mt][nt], 0, 0, 0);
        __builtin_amdgcn_s_setprio(0);
    }
}

// ---- kernel 2: MFMA GEMM, 128x128 C-tile, A from L2 via reg double-buffer.
__global__ __launch_bounds__(256, 3) void gpconv_mfma(
    const float* __restrict__ x, const unsigned short* __restrict__ kernT,
    const float* __restrict__ bias, float* __restrict__ out)
{
    __shared__ unsigned short Bs[2 * BSZ];  // 33792 B, double-buffered x window

    const int tid  = threadIdx.x;
    const int lane = tid & 63;
    const int wave = tid >> 6;
    const int lrow = lane & 15;
    const int quad = lane >> 4;
    const int wm = (wave >> 1) << 6;   // 2x2 wave grid, 64x64 each
    const int wn = (wave & 1) << 6;

    // XCD-aware remap: 4 y-blocks sharing an x-window land on the same XCD
    const int bid = blockIdx.x;              // 0..1023
    const int y   = (bid >> 3) & 3;
    const int xw  = ((bid >> 5) << 3) + (bid & 7);  // 0..255
    const int b   = xw >> 5;
    const int w0  = (xw & 31) * BN;
    const int mBase = y * BM;
    const float* xb = x + (size_t)b * (size_t)(512 * L_);
    const unsigned short* ky = kernT + (size_t)(y * NCJB) * NV * TILE;

    const int wb = wm * 64 + lane * 8;   // lane slot in frag-coalesced tile

    floatx4 acc[4][4];
    {
        const floatx4 z = {0.f, 0.f, 0.f, 0.f};
        #pragma unroll
        for (int i2 = 0; i2 < 4; i2++)
            #pragma unroll
            for (int j2 = 0; j2 < 4; j2++) acc[i2][j2] = z;
    }

    bf16x8 aX[8], aY[8];
    float brA[2][8], brB[2][8], brT[8];

    // ---- prologue: window(cjb=0) into buf0 + tile 0 into aX
    bi_half(xb, 0, w0, 0, brA);
    bi_half(xb, 0, w0, 512, brB);
    bi_tail(xb, 0, w0, brT);
    a_load(ky, wb, aX);
    st_half(Bs, 0, brA, w0);
    st_half(Bs, 512, brB, w0);
    st_tail(Bs, brT, w0);
    WAIT_LGKM_0();
    barrier_raw();

// phase p=cjb*5+v: compute CUR (tile p), prefetch tile p+1 -> NXT.
// STG: stage next window (cjb<7). Bs read buf = cjb&1, write buf = 1-(cjb&1).
#define PHASE(CUR, NXT, CJB, V, STG, LASTP)                                   \
    {                                                                         \
        const unsigned short* BsR = Bs + (((CJB) & 1) ? BSZ : 0);             \
        unsigned short*       BsW = Bs + (((CJB) & 1) ? 0 : BSZ);             \
        if ((STG) && (V) == 3) st_half(BsW, 0, brA, w0);                      \
        if ((STG) && (V) == 4) { st_half(BsW, 512, brB, w0);                  \
                                 st_tail(BsW, brT, w0); }                     \
        if (!(LASTP)) a_load(ky + (size_t)((CJB) * 5 + (V) + 1) * TILE, wb, NXT); \
        if ((STG) && (V) == 2) bi_half(xb, ((CJB) + 1) * BKCJ, w0, 0, brA);   \
        if ((STG) && (V) == 3) { bi_half(xb, ((CJB) + 1) * BKCJ, w0, 512, brB); \
                                 bi_tail(xb, ((CJB) + 1) * BKCJ, w0, brT); }  \
        compute_phase(CUR, BsR, wn, lrow, quad, (V), acc);                    \
        if ((STG) && (V) == 4) { WAIT_LGKM_0(); barrier_raw(); }              \
    }

    for (int cp = 0; cp < 3; cp++) {   // cjb pairs (0,1),(2,3),(4,5)
        const int c0 = cp * 2, c1 = c0 + 1;
        PHASE(aX, aY, c0, 0, 1, 0);
        PHASE(aY, aX, c0, 1, 1, 0);
        PHASE(aX, aY, c0, 2, 1, 0);
        PHASE(aY, aX, c0, 3, 1, 0);
        PHASE(aX, aY, c0, 4, 1, 0);
        PHASE(aY, aX, c1, 0, 1, 0);
        PHASE(aX, aY, c1, 1, 1, 0);
        PHASE(aY, aX, c1, 2, 1, 0);
        PHASE(aX, aY, c1, 3, 1, 0);
        PHASE(aY, aX, c1, 4, 1, 0);
    }
    // cjb 6 (stages window 7), cjb 7 (no staging)
    PHASE(aX, aY, 6, 0, 1, 0);
    PHASE(aY, aX, 6, 1, 1, 0);
    PHASE(aX, aY, 6, 2, 1, 0);
    PHASE(aY, aX, 6, 3, 1, 0);
    PHASE(aX, aY, 6, 4, 1, 0);
    PHASE(aY, aX, 7, 0, 0, 0);
    PHASE(aX, aY, 7, 1, 0, 0);
    PHASE(aY, aX, 7, 2, 0, 0);
    PHASE(aX, aY, 7, 3, 0, 0);
    PHASE(aY, aX, 7, 4, 0, 1);
#undef PHASE

    // ---- epilogue: C/D layout col(n)=lane&15, row(m)=quad*4+e
    #pragma unroll
    for (int mt = 0; mt < 4; mt++) {
        #pragma unroll
        for (int e = 0; e < 4; e++) {
            const int okc = mBase + wm + (mt << 4) + (quad << 2) + e;
            const float bv = bias[okc];
            float* orow = out + ((size_t)b * OKch + (size_t)okc) * L_ + w0;
            #pragma unroll
            for (int nt = 0; nt < 4; nt++) {
                const int n = wn + (nt << 4) + lrow;
                orow[n] = acc[mt][nt][e] + bv;
            }
        }
    }
}

extern "C" void kernel_launch(void* const* d_in, const int* in_sizes, int n_in,
                              void* d_out, int out_size, void* d_ws, size_t ws_size,
                              hipStream_t stream) {
    const float* x    = (const float*)d_in[0];  // (8,64,8,4096)
    const float* W    = (const float*)d_in[1];  // (5,64,64,8)
    const float* bias = (const float*)d_in[2];  // (1,64,8,1) -> [512]
    const float* G    = (const float*)d_in[3];  // (8,8,8)
    unsigned short* kernT = (unsigned short*)d_ws;  // 160 tiles x 16384 B = 2.62 MB
    float* out = (float*)d_out;

    build_kern<<<dim3(640), 256, 0, stream>>>(W, G, kernT);
    gpconv_mfma<<<dim3(1024), 256, 0, stream>>>(x, kernT, bias, out);
}

// Round 4
// 189.779 us; speedup vs baseline: 2.2431x; 2.2431x over previous
//
#include <hip/hip_runtime.h>

// GPConv1d: out[b,o,kb,w] = sum_{i,j,c,v} G[i,j,kb] W[v,c,o,i] xpad[b,c,j,w+v] + bias[o,kb]
// GEMM view: out[ok][b,w] = sum_kd kern[ok][kd] X[kd][b,w], M=512, N=32768, K=2560
// R4: occupancy back to 2 waves/SIMD (R3's ,3 forced VGPR 84 -> massive scratch
//     spill: WRITE_SIZE 65->390MB). Keep R3's Bs XOR-swizzle (conflicts 5.27M->33K)
//     and 1-barrier-per-cjb double-buffered window. NEW: in-register software
//     pipeline of B fragments -- each phase = 2 MFMA clusters (kk2=0/1); b1 frags
//     issued before cluster0, next-phase b0 issued during cluster0, so ds_read
//     latency always hides under 16 MFMA (~77cyc). A stays in reg double-buffer
//     from L2-resident frag-coalesced tiles. T5 setprio per cluster.
//     build_kern: G (2KB) staged in LDS (was 64 scattered 4B gathers/thread).

#define C_    64
#define L_    4096
#define PAD_  2
#define OKch  512

#define BM    128
#define BN    128
#define BKCJ  64
#define NCJB  8
#define NV    5
#define TILE  8192      // kern tile: 128 rows x 64 cols (16 KB), frag-coalesced
#define WIN   132       // Bs rows: w0-2 .. w0+129
#define BSZ   (WIN * 64)  // one Bs buffer: 8448 elems = 16896 B

typedef __bf16 bf16x8 __attribute__((ext_vector_type(8)));
typedef float floatx4 __attribute__((ext_vector_type(4)));

__device__ __forceinline__ unsigned short f2bf(float f) {
    unsigned int u = __float_as_uint(f);
    u += 0x7FFFu + ((u >> 16) & 1u);
    return (unsigned short)(u >> 16);
}

#define WAIT_LGKM_0() asm volatile("s_waitcnt lgkmcnt(0)" ::: "memory")

__device__ __forceinline__ void barrier_raw() {
    asm volatile("" ::: "memory");
    __builtin_amdgcn_sched_barrier(0);
    __builtin_amdgcn_s_barrier();
    __builtin_amdgcn_sched_barrier(0);
    asm volatile("" ::: "memory");
}

// ---- kernel 1: build kern in fragment-coalesced tile layout, 8 outputs/thread.
// G staged in LDS (512 floats): inner loop reads are ds_read, not L1 gathers.
__global__ __launch_bounds__(256) void build_kern(
    const float* __restrict__ W, const float* __restrict__ G,
    unsigned short* __restrict__ kernT)
{
    __shared__ float Gs[512];
    {
        const int t = threadIdx.x;
        Gs[t]       = G[t];
        Gs[t + 256] = G[t + 256];
    }
    __syncthreads();

    const int idx  = blockIdx.x * 256 + threadIdx.x;  // 0..163839
    const int lrow = idx & 15;
    const int quad = (idx >> 4) & 3;
    const int f    = (idx >> 6) & 15;
    const int mq   = f >> 1;
    const int kk2  = f & 1;
    const int t    = idx >> 10;          // (y*8+cjb)*5+v, 0..159
    const int v    = t % 5;
    const int tc   = t / 5;
    const int cjb  = tc & 7;
    const int y    = tc >> 3;
    const int m    = (mq << 4) | lrow;
    const int ok   = (y << 7) | m;
    const int o    = ok >> 3;
    const int kb   = ok & 7;
    const int c    = (cjb << 3) | (kk2 << 2) | quad;

    const float* Wp = W + (((v * C_ + c) * 64 + o) << 3);  // 8 i-contiguous
    const float4 w0 = *(const float4*)Wp;
    const float4 w1 = *(const float4*)(Wp + 4);
    const float w[8] = {w0.x, w0.y, w0.z, w0.w, w1.x, w1.y, w1.z, w1.w};

    unsigned int pk[4];
    #pragma unroll
    for (int j = 0; j < 8; j++) {
        float s = 0.f;
        #pragma unroll
        for (int i = 0; i < 8; i++)
            s += Gs[i * 64 + j * 8 + kb] * w[i];
        const unsigned short h = f2bf(s);
        if (j & 1) pk[j >> 1] |= (unsigned int)h << 16;
        else       pk[j >> 1]  = h;
    }
    uint4 uu; uu.x = pk[0]; uu.y = pk[1]; uu.z = pk[2]; uu.w = pk[3];
    *reinterpret_cast<uint4*>(
        &kernT[((size_t)t << 13) + (f << 9) + (quad << 7) + (lrow << 3)]) = uu;
}

// ---- x-window staging, split halves. Items: (kgrp=idx/132, nn=idx%132),
// halfA = idx 0..511, halfB = idx 512..1023, tail = idx 1024..1055.
__device__ __forceinline__ void bi_half(const float* xb, int cj0, int w0,
                                        int base, float br[2][8]) {
    const int tid = threadIdx.x;
    #pragma unroll
    for (int u = 0; u < 2; u++) {
        const int idx  = base + u * 256 + tid;
        const int kgrp = idx / WIN;
        const int nn   = idx - kgrp * WIN;
        int ws = w0 - PAD_ + nn;
        ws = ws < 0 ? 0 : (ws > (L_ - 1) ? (L_ - 1) : ws);
        const float* xp = xb + ((size_t)(cj0 + (kgrp << 3)) << 12) + (size_t)ws;
        #pragma unroll
        for (int r = 0; r < 8; r++)
            br[u][r] = xp[(size_t)r << 12];
    }
}

__device__ __forceinline__ void bi_tail(const float* xb, int cj0, int w0,
                                        float brT[8]) {
    const int tid = threadIdx.x;
    if ((tid & 7) == 0) {
        const int idx  = 1024 + ((tid >> 6) << 3) + ((tid >> 3) & 7);
        const int kgrp = idx / WIN;
        const int nn   = idx - kgrp * WIN;
        int ws = w0 - PAD_ + nn;
        ws = ws < 0 ? 0 : (ws > (L_ - 1) ? (L_ - 1) : ws);
        const float* xp = xb + ((size_t)(cj0 + (kgrp << 3)) << 12) + (size_t)ws;
        #pragma unroll
        for (int r = 0; r < 8; r++)
            brT[r] = xp[(size_t)r << 12];
    }
}

// store one item: row nn, 16B colslot kgrp XOR-swizzled by (nn&7)
__device__ __forceinline__ void st_item(unsigned short* Bw, int kgrp, int nn,
                                        int w0, const float br[8]) {
    const bool inb = (unsigned)(w0 - PAD_ + nn) < (unsigned)L_;
    unsigned int pk[4];
    #pragma unroll
    for (int r = 0; r < 8; r++) {
        const unsigned short h = f2bf(inb ? br[r] : 0.0f);
        if (r & 1) pk[r >> 1] |= (unsigned int)h << 16;
        else       pk[r >> 1]  = h;
    }
    uint4 uu; uu.x = pk[0]; uu.y = pk[1]; uu.z = pk[2]; uu.w = pk[3];
    *reinterpret_cast<uint4*>(&Bw[(nn << 6) + ((kgrp ^ (nn & 7)) << 3)]) = uu;
}

__device__ __forceinline__ void st_half(unsigned short* Bw, int base,
                                        const float br[2][8], int w0) {
    const int tid = threadIdx.x;
    #pragma unroll
    for (int u = 0; u < 2; u++) {
        const int idx  = base + u * 256 + tid;
        const int kgrp = idx / WIN;
        const int nn   = idx - kgrp * WIN;
        st_item(Bw, kgrp, nn, w0, br[u]);
    }
}

__device__ __forceinline__ void st_tail(unsigned short* Bw, const float brT[8],
                                        int w0) {
    const int tid = threadIdx.x;
    if ((tid & 7) == 0) {
        const int idx  = 1024 + ((tid >> 6) << 3) + ((tid >> 3) & 7);
        const int kgrp = idx / WIN;
        const int nn   = idx - kgrp * WIN;
        st_item(Bw, kgrp, nn, w0, brT);
    }
}

// ---- A-frag load: 8 contiguous-coalesced 16B loads into regs.
__device__ __forceinline__ void a_load(const unsigned short* t, int wb,
                                       bf16x8 r[8]) {
    #pragma unroll
    for (int f = 0; f < 8; f++)
        r[f] = *reinterpret_cast<const bf16x8*>(t + (f << 9) + wb);
}

// ---- B-frag batch: 4 ds_read_b128 for one kk2 group of phase v.
__device__ __forceinline__ void b_frags(const unsigned short* BsR, int wn,
                                        int lrow, int quad, int v, int kk2,
                                        bf16x8 bfr[4]) {
    const int s7  = (lrow + v) & 7;
    const int rb0 = (wn + lrow + v) << 6;
    const int col = (((kk2 << 2) | quad) ^ s7) << 3;
    #pragma unroll
    for (int nt = 0; nt < 4; nt++)
        bfr[nt] = *reinterpret_cast<const bf16x8*>(&BsR[rb0 + (nt << 10) + col]);
}

// ---- 16-MFMA cluster for one kk2 group.
__device__ __forceinline__ void mfma_cl(const bf16x8 a[8], int kk2,
                                        const bf16x8 bfr[4], floatx4 acc[4][4]) {
    __builtin_amdgcn_s_setprio(1);
    #pragma unroll
    for (int mt = 0; mt < 4; mt++)
        #pragma unroll
        for (int nt = 0; nt < 4; nt++)
            acc[mt][nt] = __builtin_amdgcn_mfma_f32_16x16x32_bf16(
                a[mt * 2 + kk2], bfr[nt], acc[mt][nt], 0, 0, 0);
    __builtin_amdgcn_s_setprio(0);
}

// ---- kernel 2: MFMA GEMM, 128x128 C-tile, A from L2 reg-dbuf, B reg-pipelined.
__global__ __launch_bounds__(256, 2) void gpconv_mfma(
    const float* __restrict__ x, const unsigned short* __restrict__ kernT,
    const float* __restrict__ bias, float* __restrict__ out)
{
    __shared__ unsigned short Bs[2 * BSZ];  // 33792 B, double-buffered x window

    const int tid  = threadIdx.x;
    const int lane = tid & 63;
    const int wave = tid >> 6;
    const int lrow = lane & 15;
    const int quad = lane >> 4;
    const int wm = (wave >> 1) << 6;   // 2x2 wave grid, 64x64 each
    const int wn = (wave & 1) << 6;

    // XCD-aware remap: 4 y-blocks sharing an x-window land on the same XCD
    const int bid = blockIdx.x;              // 0..1023
    const int y   = (bid >> 3) & 3;
    const int xw  = ((bid >> 5) << 3) + (bid & 7);  // 0..255
    const int b   = xw >> 5;
    const int w0  = (xw & 31) * BN;
    const int mBase = y * BM;
    const float* xb = x + (size_t)b * (size_t)(512 * L_);
    const unsigned short* ky = kernT + (size_t)(y * NCJB) * NV * TILE;

    const int wb = wm * 64 + lane * 8;   // lane slot in frag-coalesced tile

    floatx4 acc[4][4];
    {
        const floatx4 z = {0.f, 0.f, 0.f, 0.f};
        #pragma unroll
        for (int i2 = 0; i2 < 4; i2++)
            #pragma unroll
            for (int j2 = 0; j2 < 4; j2++) acc[i2][j2] = z;
    }

    bf16x8 aX[8], aY[8];
    bf16x8 b0[4], b1[4];
    float brA[2][8], brB[2][8], brT[8];

    // ---- prologue: window(cjb=0) into buf0 + tile 0 into aX + first b0 frags
    bi_half(xb, 0, w0, 0, brA);
    bi_half(xb, 0, w0, 512, brB);
    bi_tail(xb, 0, w0, brT);
    a_load(ky, wb, aX);
    st_half(Bs, 0, brA, w0);
    st_half(Bs, 512, brB, w0);
    st_tail(Bs, brT, w0);
    WAIT_LGKM_0();
    barrier_raw();
    b_frags(Bs, wn, lrow, quad, 0, 0, b0);

// phase p=cjb*5+v. Entering: aCUR holds tile p, b0 holds B(p,kk2=0).
// Order: b1(p) reads -> staging st/bi -> a_load(p+1) -> MFMA cl0 ->
//        b0(p+1) reads -> MFMA cl1 -> [cjb end: barrier + b0 from other buf].
#define PHASE(CUR, NXT, CJB, V, STG, LASTP)                                   \
    {                                                                         \
        const unsigned short* BsR = Bs + (((CJB) & 1) ? BSZ : 0);             \
        unsigned short*       BsW = Bs + (((CJB) & 1) ? 0 : BSZ);             \
        b_frags(BsR, wn, lrow, quad, (V), 1, b1);                             \
        if ((STG) && (V) == 3) st_half(BsW, 0, brA, w0);                      \
        if ((STG) && (V) == 4) { st_half(BsW, 512, brB, w0);                  \
                                 st_tail(BsW, brT, w0); }                     \
        if (!(LASTP)) a_load(ky + (size_t)((CJB) * 5 + (V) + 1) * TILE, wb, NXT); \
        if ((STG) && (V) == 2) bi_half(xb, ((CJB) + 1) * BKCJ, w0, 0, brA);   \
        if ((STG) && (V) == 3) { bi_half(xb, ((CJB) + 1) * BKCJ, w0, 512, brB); \
                                 bi_tail(xb, ((CJB) + 1) * BKCJ, w0, brT); }  \
        mfma_cl(CUR, 0, b0, acc);                                             \
        if ((V) < 4) b_frags(BsR, wn, lrow, quad, (V) + 1, 0, b0);            \
        mfma_cl(CUR, 1, b1, acc);                                             \
        if ((V) == 4 && (STG)) {                                              \
            WAIT_LGKM_0(); barrier_raw();                                     \
            b_frags(Bs + (((CJB) & 1) ? 0 : BSZ), wn, lrow, quad, 0, 0, b0);  \
        }                                                                     \
    }

    for (int cp = 0; cp < 3; cp++) {   // cjb pairs (0,1),(2,3),(4,5)
        const int c0 = cp * 2, c1 = c0 + 1;
        PHASE(aX, aY, c0, 0, 1, 0);
        PHASE(aY, aX, c0, 1, 1, 0);
        PHASE(aX, aY, c0, 2, 1, 0);
        PHASE(aY, aX, c0, 3, 1, 0);
        PHASE(aX, aY, c0, 4, 1, 0);
        PHASE(aY, aX, c1, 0, 1, 0);
        PHASE(aX, aY, c1, 1, 1, 0);
        PHASE(aY, aX, c1, 2, 1, 0);
        PHASE(aX, aY, c1, 3, 1, 0);
        PHASE(aY, aX, c1, 4, 1, 0);
    }
    // cjb 6 (stages window 7), cjb 7 (no staging)
    PHASE(aX, aY, 6, 0, 1, 0);
    PHASE(aY, aX, 6, 1, 1, 0);
    PHASE(aX, aY, 6, 2, 1, 0);
    PHASE(aY, aX, 6, 3, 1, 0);
    PHASE(aX, aY, 6, 4, 1, 0);
    PHASE(aY, aX, 7, 0, 0, 0);
    PHASE(aX, aY, 7, 1, 0, 0);
    PHASE(aY, aX, 7, 2, 0, 0);
    PHASE(aX, aY, 7, 3, 0, 0);
    PHASE(aY, aX, 7, 4, 0, 1);
#undef PHASE

    // ---- epilogue: C/D layout col(n)=lane&15, row(m)=quad*4+e
    #pragma unroll
    for (int mt = 0; mt < 4; mt++) {
        #pragma unroll
        for (int e = 0; e < 4; e++) {
            const int okc = mBase + wm + (mt << 4) + (quad << 2) + e;
            const float bv = bias[okc];
            float* orow = out + ((size_t)b * OKch + (size_t)okc) * L_ + w0;
            #pragma unroll
            for (int nt = 0; nt < 4; nt++) {
                const int n = wn + (nt << 4) + lrow;
                orow[n] = acc[mt][nt][e] + bv;
            }
        }
    }
}

extern "C" void kernel_launch(void* const* d_in, const int* in_sizes, int n_in,
                              void* d_out, int out_size, void* d_ws, size_t ws_size,
                              hipStream_t stream) {
    const float* x    = (const float*)d_in[0];  // (8,64,8,4096)
    const float* W    = (const float*)d_in[1];  // (5,64,64,8)
    const float* bias = (const float*)d_in[2];  // (1,64,8,1) -> [512]
    const float* G    = (const float*)d_in[3];  // (8,8,8)
    unsigned short* kernT = (unsigned short*)d_ws;  // 160 tiles x 16384 B = 2.62 MB
    float* out = (float*)d_out;

    build_kern<<<dim3(640), 256, 0, stream>>>(W, G, kernT);
    gpconv_mfma<<<dim3(1024), 256, 0, stream>>>(x, kernT, bias, out);
}

// Round 5
// 178.303 us; speedup vs baseline: 2.3875x; 1.0644x over previous
//
#include <hip/hip_runtime.h>

// GPConv1d: out[b,o,kb,w] = sum_{i,j,c,v} G[i,j,kb] W[v,c,o,i] xpad[b,c,j,w+v] + bias[o,kb]
// GEMM view: out[ok][b,w] = sum_kd kern[ok][kd] X[kd][b,w], M=512, N=32768, K=2560
// R5: (a) 4x1 wave grid: each wave owns 32 distinct A-rows -> A L2 traffic
//     1.3GB -> 0.65GB (was a ~38us L2-BW floor), A-dbuf regs halve, a_load is
//     1 base + offset:1024/2048/3072. (b) ALL K-loop global loads via inline-asm
//     with an exact manual vmcnt ledger (compiler can't see them, so no vmcnt(0)
//     drains): compute-waits 4/4/12/20/4 per v, store-waits 4; sched_barrier(0)
//     after every wait (rule #18). (c) x pre-converted to bf16 and pre-padded
//     ([4104] stride) by extra blocks of the prep kernel -> staging is pure
//     dword loads + unzip + 2x ds_write_b128 per 2-row item; no f2bf/clamp VALU.
//     Bs XOR swizzle kept (33K conflicts), 1 barrier/cjb kept, T5 setprio kept.

#define C_    64
#define L_    4096
#define PAD_  2
#define OKch  512
#define XSTR  4104      // padded bf16 x row stride (elems); halo [0,1],[4098,4099]

#define BM    128
#define BN    128
#define BKCJ  64
#define NCJB  8
#define NV    5
#define TILE  8192      // kern tile: 128 rows x 64 cols (16 KB), frag-coalesced
#define WIN   132       // Bs rows: w0-2 .. w0+129
#define BSZ   (WIN * 64)  // one Bs buffer: 8448 elems = 16896 B

typedef __bf16 bf16x8 __attribute__((ext_vector_type(8)));
typedef float floatx4 __attribute__((ext_vector_type(4)));

__device__ __forceinline__ unsigned short f2bf(float f) {
    unsigned int u = __float_as_uint(f);
    u += 0x7FFFu + ((u >> 16) & 1u);
    return (unsigned short)(u >> 16);
}

#define WAIT_LGKM_0() asm volatile("s_waitcnt lgkmcnt(0)" ::: "memory")
#define WAITV_(N) asm volatile("s_waitcnt vmcnt(" #N ")" ::: "memory")
#define WAITV(N) do { WAITV_(N); __builtin_amdgcn_sched_barrier(0); } while (0)

__device__ __forceinline__ void barrier_raw() {
    asm volatile("" ::: "memory");
    __builtin_amdgcn_sched_barrier(0);
    __builtin_amdgcn_s_barrier();
    __builtin_amdgcn_sched_barrier(0);
    asm volatile("" ::: "memory");
}

// manual global loads (invisible to compiler's waitcnt inserter)
#define GLD_U32(dst, ptr) \
    asm volatile("global_load_dword %0, %1, off" : "=&v"(dst) : "v"(ptr))
#define GLD_A4(a0, a1, a2, a3, ptr)                          \
    asm volatile("global_load_dwordx4 %0, %4, off\n\t"       \
                 "global_load_dwordx4 %1, %4, off offset:1024\n\t" \
                 "global_load_dwordx4 %2, %4, off offset:2048\n\t" \
                 "global_load_dwordx4 %3, %4, off offset:3072"     \
                 : "=&v"(a0), "=&v"(a1), "=&v"(a2), "=&v"(a3) : "v"(ptr))

// ---- kernel 1: prep = build_kern (blocks 0..639) + x->bf16 pad (blocks 640..4735)
__global__ __launch_bounds__(256) void prep(
    const float* __restrict__ W, const float* __restrict__ G,
    const float* __restrict__ x,
    unsigned short* __restrict__ kernT, unsigned short* __restrict__ xp)
{
    const int bid = blockIdx.x;
    const int tid = threadIdx.x;
    if (bid < 640) {
        __shared__ float Gs[512];
        Gs[tid] = G[tid];
        Gs[tid + 256] = G[tid + 256];
        __syncthreads();

        const int idx  = bid * 256 + tid;    // 0..163839
        const int lrow = idx & 15;
        const int quad = (idx >> 4) & 3;
        const int f    = (idx >> 6) & 15;
        const int mq   = f >> 1;
        const int kk2  = f & 1;
        const int t    = idx >> 10;          // (y*8+cjb)*5+v, 0..159
        const int v    = t % 5;
        const int tc   = t / 5;
        const int cjb  = tc & 7;
        const int y    = tc >> 3;
        const int m    = (mq << 4) | lrow;
        const int ok   = (y << 7) | m;
        const int o    = ok >> 3;
        const int kb   = ok & 7;
        const int c    = (cjb << 3) | (kk2 << 2) | quad;

        const float* Wp = W + (((v * C_ + c) * 64 + o) << 3);
        const float4 w0 = *(const float4*)Wp;
        const float4 w1 = *(const float4*)(Wp + 4);
        const float w[8] = {w0.x, w0.y, w0.z, w0.w, w1.x, w1.y, w1.z, w1.w};

        unsigned int pk[4];
        #pragma unroll
        for (int j = 0; j < 8; j++) {
            float s = 0.f;
            #pragma unroll
            for (int i = 0; i < 8; i++)
                s += Gs[i * 64 + j * 8 + kb] * w[i];
            const unsigned short h = f2bf(s);
            if (j & 1) pk[j >> 1] |= (unsigned int)h << 16;
            else       pk[j >> 1]  = h;
        }
        uint4 uu; uu.x = pk[0]; uu.y = pk[1]; uu.z = pk[2]; uu.w = pk[3];
        *reinterpret_cast<uint4*>(
            &kernT[((size_t)t << 13) + (f << 9) + (quad << 7) + (lrow << 3)]) = uu;
    } else {
        const int row = bid - 640;           // 0..4095 = b*512 + cj
        const float* src = x + (size_t)row * L_;
        unsigned short* dst = xp + (size_t)row * XSTR;
        #pragma unroll
        for (int i = 0; i < 4; i++) {
            const int p = (i * 256 + tid) << 2;
            const float4 fv = *reinterpret_cast<const float4*>(src + p);
            const unsigned int u0 = (unsigned int)f2bf(fv.x) | ((unsigned int)f2bf(fv.y) << 16);
            const unsigned int u1 = (unsigned int)f2bf(fv.z) | ((unsigned int)f2bf(fv.w) << 16);
            *reinterpret_cast<unsigned int*>(dst + 2 + p) = u0;
            *reinterpret_cast<unsigned int*>(dst + 4 + p) = u1;
        }
        if (tid == 0) {
            *reinterpret_cast<unsigned int*>(dst) = 0u;          // w' 0,1
            *reinterpret_cast<unsigned int*>(dst + 4098) = 0u;   // w' 4098,4099
        }
    }
}

// ---- staging helpers: item = (kgrp=idx/66, wpair=idx%66) covers rows nn,nn+1
__device__ __forceinline__ void bi_round(const unsigned short* xp, int cj0,
                                         int w0, int round, unsigned int (&d)[8]) {
    const int idx  = round * 256 + (int)threadIdx.x;
    const int kgrp = idx / 66;
    const int wp   = idx - kgrp * 66;
    const unsigned short* p =
        xp + (size_t)(cj0 + (kgrp << 3)) * XSTR + (size_t)(w0 + (wp << 1));
    GLD_U32(d[0], p);
    GLD_U32(d[1], p + XSTR);
    GLD_U32(d[2], p + 2 * XSTR);
    GLD_U32(d[3], p + 3 * XSTR);
    GLD_U32(d[4], p + 4 * XSTR);
    GLD_U32(d[5], p + 5 * XSTR);
    GLD_U32(d[6], p + 6 * XSTR);
    GLD_U32(d[7], p + 7 * XSTR);
}

__device__ __forceinline__ void bi_tail(const unsigned short* xp, int cj0,
                                        int w0, unsigned int (&d)[8]) {
    const int lane = (int)threadIdx.x & 63;
    const int wave = (int)threadIdx.x >> 6;
    if ((lane & 15) == 0) {
        const int idx  = 512 + (wave << 2) + (lane >> 4);
        const int kgrp = idx / 66;
        const int wp   = idx - kgrp * 66;
        const unsigned short* p =
            xp + (size_t)(cj0 + (kgrp << 3)) * XSTR + (size_t)(w0 + (wp << 1));
        GLD_U32(d[0], p);
        GLD_U32(d[1], p + XSTR);
        GLD_U32(d[2], p + 2 * XSTR);
        GLD_U32(d[3], p + 3 * XSTR);
        GLD_U32(d[4], p + 4 * XSTR);
        GLD_U32(d[5], p + 5 * XSTR);
        GLD_U32(d[6], p + 6 * XSTR);
        GLD_U32(d[7], p + 7 * XSTR);
    }
}

__device__ __forceinline__ void st_item(unsigned short* Bw, int kgrp, int nn,
                                        const unsigned int (&d)[8]) {
    const unsigned int lo0 = (d[0] & 0xffffu) | (d[1] << 16);
    const unsigned int hi0 = (d[0] >> 16)     | (d[1] & 0xffff0000u);
    const unsigned int lo1 = (d[2] & 0xffffu) | (d[3] << 16);
    const unsigned int hi1 = (d[2] >> 16)     | (d[3] & 0xffff0000u);
    const unsigned int lo2 = (d[4] & 0xffffu) | (d[5] << 16);
    const unsigned int hi2 = (d[4] >> 16)     | (d[5] & 0xffff0000u);
    const unsigned int lo3 = (d[6] & 0xffffu) | (d[7] << 16);
    const unsigned int hi3 = (d[6] >> 16)     | (d[7] & 0xffff0000u);
    const int s = kgrp ^ (nn & 7);
    uint4 Lv; Lv.x = lo0; Lv.y = lo1; Lv.z = lo2; Lv.w = lo3;
    uint4 Hv; Hv.x = hi0; Hv.y = hi1; Hv.z = hi2; Hv.w = hi3;
    *reinterpret_cast<uint4*>(&Bw[(nn << 6) + (s << 3)]) = Lv;
    *reinterpret_cast<uint4*>(&Bw[((nn + 1) << 6) + ((s ^ 1) << 3)]) = Hv;
}

__device__ __forceinline__ void st_round(unsigned short* Bw, int round,
                                         const unsigned int (&d)[8]) {
    const int idx  = round * 256 + (int)threadIdx.x;
    const int kgrp = idx / 66;
    const int wp   = idx - kgrp * 66;
    st_item(Bw, kgrp, wp << 1, d);
}

__device__ __forceinline__ void st_tail(unsigned short* Bw,
                                        const unsigned int (&d)[8]) {
    const int lane = (int)threadIdx.x & 63;
    const int wave = (int)threadIdx.x >> 6;
    if ((lane & 15) == 0) {
        const int idx  = 512 + (wave << 2) + (lane >> 4);
        const int kgrp = idx / 66;
        const int wp   = idx - kgrp * 66;
        st_item(Bw, kgrp, wp << 1, d);
    }
}

// ---- B-frag reads for one kk2 group: 8 x ds_read_b128, conflict-free (swizzle)
__device__ __forceinline__ void bfread(const unsigned short* BsR, int v, int kk2,
                                       int lrow, int quad, bf16x8 (&f)[8]) {
    const int s7  = (lrow + v) & 7;
    const int col = ((((kk2) << 2) | quad) ^ s7) << 3;
    const int rb  = (lrow + v) << 6;
    #pragma unroll
    for (int nt = 0; nt < 8; nt++)
        f[nt] = *reinterpret_cast<const bf16x8*>(&BsR[rb + (nt << 10) + col]);
}

__device__ __forceinline__ void cl(const bf16x8 (&a)[4], int kk2,
                                   const bf16x8 (&f)[8], floatx4 (&acc)[2][8]) {
    __builtin_amdgcn_s_setprio(1);
    #pragma unroll
    for (int mt = 0; mt < 2; mt++)
        #pragma unroll
        for (int nt = 0; nt < 8; nt++)
            acc[mt][nt] = __builtin_amdgcn_mfma_f32_16x16x32_bf16(
                a[mt * 2 + kk2], f[nt], acc[mt][nt], 0, 0, 0);
    __builtin_amdgcn_s_setprio(0);
}

// ---- kernel 2: MFMA GEMM, 128x128 C-tile, 4x1 wave grid, manual vmcnt pipeline
__global__ __launch_bounds__(256, 2) void gpconv_mfma(
    const unsigned short* __restrict__ xp, const unsigned short* __restrict__ kernT,
    const float* __restrict__ bias, float* __restrict__ out)
{
    __shared__ unsigned short Bs[2 * BSZ];  // 33792 B, double-buffered x window

    const int tid  = threadIdx.x;
    const int lane = tid & 63;
    const int wave = tid >> 6;
    const int lrow = lane & 15;
    const int quad = lane >> 4;

    // XCD-aware remap: 4 y-blocks sharing an x-window land on the same XCD
    const int bid = blockIdx.x;              // 0..1023
    const int y   = (bid >> 3) & 3;
    const int xw  = ((bid >> 5) << 3) + (bid & 7);  // 0..255
    const int b   = xw >> 5;
    const int w0  = (xw & 31) * BN;
    const int mBase = y * BM;
    const unsigned short* xb = xp + (size_t)b * (size_t)(512 * XSTR);
    const unsigned short* ky = kernT + (size_t)(y * NCJB) * NV * TILE;
    const unsigned short* abase = ky + (wave << 11) + (lane << 3);  // wave's f0 slot

    floatx4 acc[2][8];
    {
        const floatx4 z = {0.f, 0.f, 0.f, 0.f};
        #pragma unroll
        for (int i2 = 0; i2 < 2; i2++)
            #pragma unroll
            for (int j2 = 0; j2 < 8; j2++) acc[i2][j2] = z;
    }

    bf16x8 aX[4], aY[4];
    unsigned int dA[8], dB[8], dT[8];

    // ---- prologue: window(cjb=0) + tile 0 -> aX.  queue: [bi24, A0(4)]
    bi_round(xb, 0, w0, 0, dA);
    bi_round(xb, 0, w0, 1, dB);
    bi_tail(xb, 0, w0, dT);
    GLD_A4(aX[0], aX[1], aX[2], aX[3], abase);
    WAITV(4);                       // bi done; A0 in flight
    st_round(Bs, 0, dA);
    st_round(Bs, 1, dB);
    st_tail(Bs, dT);
    WAIT_LGKM_0();
    barrier_raw();                  // invariant entering loop: pending [A0]

// phase p=CJB*5+V. Ledger (STG): V0:[A,A']w4 V1:w4 V2:+bi8 w12 V3:st(w4)+bi16 w20
// V4:st(w4) w4 +barrier.  Non-STG cjb: w4 everywhere, last phase w0.
#define PHASE(CUR, NXT, CJB, V, STG, LASTP, WCMP)                             \
    {                                                                         \
        const unsigned short* BsR = Bs + (((CJB) & 1) ? BSZ : 0);             \
        unsigned short*       BsW = Bs + (((CJB) & 1) ? 0 : BSZ);             \
        if ((STG) && (V) == 3) { WAITV(4); st_round(BsW, 0, dA); }            \
        if ((STG) && (V) == 4) { WAITV(4); st_round(BsW, 1, dB);              \
                                 st_tail(BsW, dT); }                          \
        bf16x8 f0[8], f1[8];                                                  \
        bfread(BsR, (V), 0, lrow, quad, f0);                                  \
        if ((STG) && (V) == 2) bi_round(xb, ((CJB) + 1) * BKCJ, w0, 0, dA);   \
        if ((STG) && (V) == 3) { bi_round(xb, ((CJB) + 1) * BKCJ, w0, 1, dB); \
                                 bi_tail(xb, ((CJB) + 1) * BKCJ, w0, dT); }   \
        if (!(LASTP)) GLD_A4(NXT[0], NXT[1], NXT[2], NXT[3],                  \
                             abase + (size_t)((CJB) * 5 + (V) + 1) * TILE);   \
        WAITV(WCMP);                                                          \
        cl(CUR, 0, f0, acc);                                                  \
        bfread(BsR, (V), 1, lrow, quad, f1);                                  \
        cl(CUR, 1, f1, acc);                                                  \
        if ((STG) && (V) == 4) { WAIT_LGKM_0(); barrier_raw(); }              \
    }

    for (int cp = 0; cp < 3; cp++) {   // cjb pairs (0,1),(2,3),(4,5)
        const int c0 = cp * 2, c1 = c0 + 1;
        PHASE(aX, aY, c0, 0, 1, 0, 4);
        PHASE(aY, aX, c0, 1, 1, 0, 4);
        PHASE(aX, aY, c0, 2, 1, 0, 12);
        PHASE(aY, aX, c0, 3, 1, 0, 20);
        PHASE(aX, aY, c0, 4, 1, 0, 4);
        PHASE(aY, aX, c1, 0, 1, 0, 4);
        PHASE(aX, aY, c1, 1, 1, 0, 4);
        PHASE(aY, aX, c1, 2, 1, 0, 12);
        PHASE(aX, aY, c1, 3, 1, 0, 20);
        PHASE(aY, aX, c1, 4, 1, 0, 4);
    }
    // cjb 6 (stages window 7), cjb 7 (no staging)
    PHASE(aX, aY, 6, 0, 1, 0, 4);
    PHASE(aY, aX, 6, 1, 1, 0, 4);
    PHASE(aX, aY, 6, 2, 1, 0, 12);
    PHASE(aY, aX, 6, 3, 1, 0, 20);
    PHASE(aX, aY, 6, 4, 1, 0, 4);
    PHASE(aY, aX, 7, 0, 0, 0, 4);
    PHASE(aX, aY, 7, 1, 0, 0, 4);
    PHASE(aY, aX, 7, 2, 0, 0, 4);
    PHASE(aX, aY, 7, 3, 0, 0, 4);
    PHASE(aY, aX, 7, 4, 0, 1, 0);
#undef PHASE

    // ---- epilogue: C/D layout col(n)=lane&15, row(m)=quad*4+e
    #pragma unroll
    for (int mt = 0; mt < 2; mt++) {
        #pragma unroll
        for (int e = 0; e < 4; e++) {
            const int okc = mBase + (wave << 5) + (mt << 4) + (quad << 2) + e;
            const float bv = bias[okc];
            float* orow = out + ((size_t)b * OKch + (size_t)okc) * L_ + w0;
            #pragma unroll
            for (int nt = 0; nt < 8; nt++) {
                const int n = (nt << 4) + lrow;
                orow[n] = acc[mt][nt][e] + bv;
            }
        }
    }
}

extern "C" void kernel_launch(void* const* d_in, const int* in_sizes, int n_in,
                              void* d_out, int out_size, void* d_ws, size_t ws_size,
                              hipStream_t stream) {
    const float* x    = (const float*)d_in[0];  // (8,64,8,4096)
    const float* W    = (const float*)d_in[1];  // (5,64,64,8)
    const float* bias = (const float*)d_in[2];  // (1,64,8,1) -> [512]
    const float* G    = (const float*)d_in[3];  // (8,8,8)
    unsigned short* kernT = (unsigned short*)d_ws;                       // 2.62 MB
    unsigned short* xp    = (unsigned short*)((char*)d_ws + (4 << 20));  // 33.6 MB
    float* out = (float*)d_out;

    prep<<<dim3(640 + 4096), 256, 0, stream>>>(W, G, x, kernT, xp);
    gpconv_mfma<<<dim3(1024), 256, 0, stream>>>(xp, kernT, bias, out);
}